// Round 11
// baseline (2232.458 us; speedup 1.0000x reference)
//
#include <hip/hip_runtime.h>
#include <cstddef>

// ---------------------------------------------------------------------------
// 3-layer GCN: per layer  h = A_in @ W ;  agg[c] = sum_e coef[e]*h[row_e] (+self) + b
// BN+ReLU fused into the NEXT layer's GEMM A-load.
// Edge aggregation uses a per-call counting sort by destination (no atomics in
// the hot loop). Degree+count histograms fused into one packed u64 atomic per
// edge (atomics are 32B memory-side RMW: WRITE_SIZE == 32B * n_atomics).
// GEMM: TM4xTN8 microtile, launch_bounds(256,4) for 4 waves/SIMD (VGPR<=128;
// round-5 TM8 config hit VGPR=140 -> 2 waves/SIMD -> Occupancy 8.8%, 220us),
// register double-buffer: issue next K-tile loads before compute phase.
// ---------------------------------------------------------------------------

#define WS_ALIGN(x) (((x) + 255) & ~(size_t)255)

// ---- init: packed deg/count = 0, BN stat accumulators = 0 ------------------
__global__ __launch_bounds__(256) void init_kernel(unsigned long long* packed,
                                                   float* sums, float* sumsq,
                                                   int N) {
  int i = blockIdx.x * 256 + threadIdx.x;
  if (i < N) packed[i] = 0ull;
  if (i < 128) { sums[i] = 0.f; sumsq[i] = 0.f; }
}

// ---- per-edge: ONE packed u64 atomic = {count<<40 | fixedpoint(w)} ---------
__global__ __launch_bounds__(256) void edge_deg_kernel(const int* __restrict__ cols,
                                                       const float* __restrict__ w,
                                                       unsigned long long* __restrict__ packed,
                                                       int E) {
  int e = blockIdx.x * 256 + threadIdx.x;
  if (e >= E) return;
  int c = cols[e];
  unsigned long long v = (1ull << 40) |
                         (unsigned long long)(unsigned int)__float2uint_rn(w[e] * 1048576.0f);
  atomicAdd(&packed[c], v);
}

__global__ __launch_bounds__(256) void dinv_kernel(const unsigned long long* __restrict__ packed,
                                                   float* __restrict__ dinv, int N) {
  int i = blockIdx.x * 256 + threadIdx.x;
  if (i < N) {
    float deg = 1.0f + (float)(packed[i] & 0xFFFFFFFFFFull) * (1.0f / 1048576.0f);
    dinv[i] = rsqrtf(deg);   // deg >= 1 always (self loop)
  }
}

// ---- 3-kernel exclusive scan of hist(=packed>>40) -> offsets (chunk=2048) --
__global__ __launch_bounds__(256) void scan1_kernel(const unsigned long long* __restrict__ packed,
                                                    int* __restrict__ bsum, int N) {
  int base = blockIdx.x * 2048 + threadIdx.x * 8;
  int s = 0;
#pragma unroll
  for (int j = 0; j < 8; ++j) { int i = base + j; if (i < N) s += (int)(packed[i] >> 40); }
  __shared__ int ls[256];
  ls[threadIdx.x] = s; __syncthreads();
  for (int st = 128; st > 0; st >>= 1) {
    if (threadIdx.x < st) ls[threadIdx.x] += ls[threadIdx.x + st];
    __syncthreads();
  }
  if (threadIdx.x == 0) bsum[blockIdx.x] = ls[0];
}

// single-wave shuffle scan (nb <= 64; nb = ceil(N/2048) = 49 for N=100K)
__global__ void scan2_kernel(const int* __restrict__ bsum, int* __restrict__ bpref,
                             int nb, int* __restrict__ offsets, int N) {
  int lane = threadIdx.x;  // 64 threads
  int mine = (lane < nb) ? bsum[lane] : 0;
  int v = mine;
  for (int st = 1; st < 64; st <<= 1) {
    int t = __shfl_up(v, st, 64);
    if (lane >= st) v += t;
  }
  if (lane < nb) bpref[lane] = v - mine;   // exclusive
  if (lane == 63) offsets[N] = v;          // total == E
}

__global__ __launch_bounds__(256) void scan3_kernel(const unsigned long long* __restrict__ packed,
                                                    const int* __restrict__ bpref,
                                                    int* __restrict__ offsets,
                                                    int* __restrict__ cursors, int N) {
  int tid = threadIdx.x;
  int base = blockIdx.x * 2048 + tid * 8;
  int v[8]; int s = 0;
#pragma unroll
  for (int j = 0; j < 8; ++j) {
    int i = base + j;
    v[j] = (i < N) ? (int)(packed[i] >> 40) : 0;
    s += v[j];
  }
  __shared__ int ls[256];
  ls[tid] = s; __syncthreads();
  for (int st = 1; st < 256; st <<= 1) {
    int t = (tid >= st) ? ls[tid - st] : 0;
    __syncthreads();
    ls[tid] += t;
    __syncthreads();
  }
  int run = bpref[blockIdx.x] + (ls[tid] - s);   // exclusive prefix for this thread
#pragma unroll
  for (int j = 0; j < 8; ++j) {
    int i = base + j;
    if (i < N) { offsets[i] = run; cursors[i] = run; run += v[j]; }
  }
}

// ---- scatter edges into CSR-by-destination, fusing coef computation --------
__global__ __launch_bounds__(256) void scatter_kernel(const int* __restrict__ rows,
                                                      const int* __restrict__ cols,
                                                      const float* __restrict__ w,
                                                      const float* __restrict__ dinv,
                                                      int* __restrict__ cursors,
                                                      int* __restrict__ srow,
                                                      float* __restrict__ scoef, int E) {
  int e = blockIdx.x * 256 + threadIdx.x;
  if (e >= E) return;
  int r = rows[e], c = cols[e];
  int pos = atomicAdd(&cursors[c], 1);
  srow[pos] = r;
  scoef[pos] = dinv[r] * w[e] * dinv[c];
}

// ---- fp32 GEMM, TM4xTN8, reg-double-buffered, fused BN+ReLU on A -----------
// Split-4 ownership on A rows (TM path) and B cols so every ds_read_b128 is
// conflict-free. As row pad +1: staging-write bank = (k+r)%32 -> <=2-way.
// launch_bounds(256,4): VGPR<=128 -> 4 waves/SIMD -> 4 blocks/CU (LDS 24.7KB).
template <int K, int F, int BM, bool PRO>
__global__ __launch_bounds__(256, 4)
void gemm_kernel(const float* __restrict__ A, const float* __restrict__ W,
                 float* __restrict__ out, int M,
                 const float* __restrict__ alpha, const float* __restrict__ beta) {
  constexpr int BK = 32;
  constexpr int TM = 4, TN = 8;
  constexpr int TX = F / TN;
  constexpr int TY = BM / TM;
  constexpr int NA = BM / 32;           // A float4s per thread per K-step
  constexpr int NB = (BK * F) / 1024;   // B float4s per thread per K-step
  static_assert(TX * TY == 256, "bad tile config");
  __shared__ float As[BK][BM + 1];   // transposed: As[k][row], padded
  __shared__ float Bs[BK][F];
  const int tid = threadIdx.x;
  const int tx = tid % TX;
  const int ty = tid / TX;
  const int row0 = blockIdx.x * BM;
  float acc[TM][TN];
#pragma unroll
  for (int m = 0; m < TM; ++m)
#pragma unroll
    for (int n = 0; n < TN; ++n) acc[m][n] = 0.f;

  const int ar = tid >> 3;         // 0..31 (row within 32-row pass)
  const int ak = (tid & 7) * 4;    // k offset (float4)

  float4 rA[NA], rB[NB], rAl, rBe;

  auto load_tile = [&](int k0) {
#pragma unroll
    for (int p = 0; p < NA; ++p) {
      int gr = row0 + p * 32 + ar;
      rA[p] = (gr < M) ? *(const float4*)(A + (size_t)gr * K + k0 + ak)
                       : make_float4(0.f, 0.f, 0.f, 0.f);
    }
#pragma unroll
    for (int p = 0; p < NB; ++p) {
      int idx = p * 256 + tid;            // float4 index
      int kk = idx / (F / 4);
      int cc = (idx % (F / 4)) * 4;
      rB[p] = *(const float4*)(W + (size_t)(k0 + kk) * F + cc);
    }
    if constexpr (PRO) {
      rAl = *(const float4*)(alpha + k0 + ak);
      rBe = *(const float4*)(beta + k0 + ak);
    }
  };

  auto store_tile = [&]() {
#pragma unroll
    for (int p = 0; p < NA; ++p) {
      float4 v = rA[p];
      if constexpr (PRO) {
        v.x = fmaxf(fmaf(v.x, rAl.x, rBe.x), 0.f);
        v.y = fmaxf(fmaf(v.y, rAl.y, rBe.y), 0.f);
        v.z = fmaxf(fmaf(v.z, rAl.z, rBe.z), 0.f);
        v.w = fmaxf(fmaf(v.w, rAl.w, rBe.w), 0.f);
      }
      int r = p * 32 + ar;
      As[ak + 0][r] = v.x; As[ak + 1][r] = v.y;
      As[ak + 2][r] = v.z; As[ak + 3][r] = v.w;
    }
#pragma unroll
    for (int p = 0; p < NB; ++p) {
      int idx = p * 256 + tid;
      int kk = idx / (F / 4);
      int cc = (idx % (F / 4)) * 4;
      *(float4*)&Bs[kk][cc] = rB[p];
    }
  };

  auto compute = [&]() {
#pragma unroll
    for (int kk = 0; kk < BK; ++kk) {
      float a[TM], b[TN];
      *(float4*)&a[0] = *(const float4*)&As[kk][ty * 4];
      *(float4*)&b[0] = *(const float4*)&Bs[kk][tx * 4];
      *(float4*)&b[4] = *(const float4*)&Bs[kk][F / 2 + tx * 4];
#pragma unroll
      for (int m = 0; m < TM; ++m)
#pragma unroll
        for (int n = 0; n < TN; ++n)
          acc[m][n] = fmaf(a[m], b[n], acc[m][n]);
    }
  };

  // prologue: tile 0
  load_tile(0);
  store_tile();
  __syncthreads();
  // main: issue next-tile loads, compute current, then store after barrier
  for (int k0 = BK; k0 < K; k0 += BK) {
    load_tile(k0);     // global loads in flight during compute
    compute();
    __syncthreads();   // all waves done reading current LDS tile
    store_tile();      // implicit waitcnt on the loads
    __syncthreads();
  }
  compute();           // last tile

#pragma unroll
  for (int m = 0; m < TM; ++m) {
    int gr = row0 + ty * 4 + m;
    if (gr < M) {
      float4* o0 = (float4*)(out + (size_t)gr * F + tx * 4);
      float4* o1 = (float4*)(out + (size_t)gr * F + F / 2 + tx * 4);
      *o0 = make_float4(acc[m][0], acc[m][1], acc[m][2], acc[m][3]);
      *o1 = make_float4(acc[m][4], acc[m][5], acc[m][6], acc[m][7]);
    }
  }
}

// ---- aggregation: one wave per destination node, CSR segment ---------------
// Random-gather over L3-resident h: latency-bound, so 4-deep edge ILP.
template <int F>
__global__ __launch_bounds__(256)
void agg_kernel(const float* __restrict__ h, const int* __restrict__ srow,
                const float* __restrict__ scoef, const int* __restrict__ off,
                const float* __restrict__ dinv, const float* __restrict__ bias,
                float* __restrict__ out, int N) {
  constexpr int VPL = F / 64;   // floats per lane (2 for F=128, 1 for F=64)
  int wid = blockIdx.x * 4 + (threadIdx.x >> 6);
  if (wid >= N) return;
  int lane = threadIdx.x & 63;
  float d = dinv[wid];
  float acc[VPL];
  {
    const float* hc = h + (size_t)wid * F;
#pragma unroll
    for (int j = 0; j < VPL; ++j)
      acc[j] = d * d * hc[lane * VPL + j] + bias[lane * VPL + j];
  }
  int s = off[wid], e = off[wid + 1];
  int i = s;
  for (; i + 4 <= e; i += 4) {
    int r0 = srow[i], r1 = srow[i + 1], r2 = srow[i + 2], r3 = srow[i + 3];
    float c0 = scoef[i], c1 = scoef[i + 1], c2 = scoef[i + 2], c3 = scoef[i + 3];
    const float* h0 = h + (size_t)r0 * F;
    const float* h1 = h + (size_t)r1 * F;
    const float* h2 = h + (size_t)r2 * F;
    const float* h3 = h + (size_t)r3 * F;
    float v0[VPL], v1[VPL], v2[VPL], v3[VPL];
#pragma unroll
    for (int j = 0; j < VPL; ++j) v0[j] = h0[lane * VPL + j];
#pragma unroll
    for (int j = 0; j < VPL; ++j) v1[j] = h1[lane * VPL + j];
#pragma unroll
    for (int j = 0; j < VPL; ++j) v2[j] = h2[lane * VPL + j];
#pragma unroll
    for (int j = 0; j < VPL; ++j) v3[j] = h3[lane * VPL + j];
#pragma unroll
    for (int j = 0; j < VPL; ++j) acc[j] = fmaf(c0, v0[j], acc[j]);
#pragma unroll
    for (int j = 0; j < VPL; ++j) acc[j] = fmaf(c1, v1[j], acc[j]);
#pragma unroll
    for (int j = 0; j < VPL; ++j) acc[j] = fmaf(c2, v2[j], acc[j]);
#pragma unroll
    for (int j = 0; j < VPL; ++j) acc[j] = fmaf(c3, v3[j], acc[j]);
  }
  for (; i < e; ++i) {
    int r0 = srow[i]; float c0 = scoef[i];
    const float* h0 = h + (size_t)r0 * F;
#pragma unroll
    for (int j = 0; j < VPL; ++j) acc[j] = fmaf(c0, h0[lane * VPL + j], acc[j]);
  }
  float* oc = out + (size_t)wid * F;
#pragma unroll
  for (int j = 0; j < VPL; ++j) oc[lane * VPL + j] = acc[j];
}

// ---- BN stats: per-block partial sums over 64 rows, atomics into 128 accs --
__global__ __launch_bounds__(256) void stats_kernel(const float* __restrict__ x, int N,
                                                    float* __restrict__ sums,
                                                    float* __restrict__ sumsq) {
  int f = threadIdx.x & 127;
  int half = threadIdx.x >> 7;   // 0 or 1
  int rend = min(N, (int)(blockIdx.x + 1) * 64);
  float s = 0.f, ss = 0.f;
  for (int r = blockIdx.x * 64 + half; r < rend; r += 2) {
    float v = x[(size_t)r * 128 + f];
    s += v; ss += v * v;
  }
  __shared__ float ls[256], lss[256];
  ls[threadIdx.x] = s; lss[threadIdx.x] = ss;
  __syncthreads();
  if (half == 0) {
    s += ls[threadIdx.x + 128];
    ss += lss[threadIdx.x + 128];
    atomicAdd(&sums[f], s);
    atomicAdd(&sumsq[f], ss);
  }
}

// ---- fold stats + g/be into per-feature alpha/beta; re-zero accumulators ---
__global__ void finalize_kernel(const float* __restrict__ g, const float* __restrict__ be,
                                float* __restrict__ sums, float* __restrict__ sumsq,
                                float* __restrict__ alpha, float* __restrict__ beta,
                                float invN) {
  int f = threadIdx.x;  // 128 threads
  float mu = sums[f] * invN;
  float var = sumsq[f] * invN - mu * mu;
  float a = g[f] * rsqrtf(var + 1e-5f);
  alpha[f] = a;
  beta[f] = be[f] - mu * a;
  sums[f] = 0.f; sumsq[f] = 0.f;   // ready for next BN layer
}

extern "C" void kernel_launch(void* const* d_in, const int* in_sizes, int n_in,
                              void* d_out, int out_size, void* d_ws, size_t ws_size,
                              hipStream_t stream) {
  const float* x   = (const float*)d_in[0];
  const int*   ei  = (const int*)d_in[1];
  const float* ew  = (const float*)d_in[2];
  const float* W1  = (const float*)d_in[3];
  const float* b1  = (const float*)d_in[4];
  const float* g1  = (const float*)d_in[5];
  const float* be1 = (const float*)d_in[6];
  const float* W2  = (const float*)d_in[7];
  const float* b2  = (const float*)d_in[8];
  const float* g2  = (const float*)d_in[9];
  const float* be2 = (const float*)d_in[10];
  const float* W3  = (const float*)d_in[11];
  const float* b3  = (const float*)d_in[12];

  const int N = in_sizes[0] / 256;
  const int E = in_sizes[2];
  const int* rows = ei;        // edge_index[0]
  const int* cols = ei + E;    // edge_index[1]

  // ---- carve workspace ----
  char* p = (char*)d_ws;
  auto carve = [&](size_t bytes) { char* q = p; p += WS_ALIGN(bytes); return (void*)q; };
  unsigned long long* packed = (unsigned long long*)carve((size_t)N * 8);
  float* dinv    = (float*)carve((size_t)N * 4);
  int*   offsets = (int*)  carve(((size_t)N + 1) * 4);
  int*   cursors = (int*)  carve((size_t)N * 4);
  int*   bsum    = (int*)  carve(256 * 4);
  int*   bpref   = (int*)  carve(256 * 4);
  int*   srow    = (int*)  carve((size_t)E * 4);
  float* scoef   = (float*)carve((size_t)E * 4);
  float* h       = (float*)carve((size_t)N * 128 * 4);
  float* agg     = (float*)carve((size_t)N * 128 * 4);
  float* sums    = (float*)carve(128 * 4);
  float* sumsq   = (float*)carve(128 * 4);
  float* alpha   = (float*)carve(128 * 4);
  float* beta    = (float*)carve(128 * 4);
  (void)ws_size; (void)n_in; (void)out_size;

  const int gN = (N + 255) / 256;
  const int gE = (E + 255) / 256;
  const int nb = (N + 2047) / 2048;   // <= 64 required by scan2 (49 for N=100K)

  // ---- shared precompute: packed deg/count, dinv, CSR-by-col sort, coef ----
  init_kernel<<<gN, 256, 0, stream>>>(packed, sums, sumsq, N);
  edge_deg_kernel<<<gE, 256, 0, stream>>>(cols, ew, packed, E);
  dinv_kernel<<<gN, 256, 0, stream>>>(packed, dinv, N);
  scan1_kernel<<<nb, 256, 0, stream>>>(packed, bsum, N);
  scan2_kernel<<<1, 64, 0, stream>>>(bsum, bpref, nb, offsets, N);
  scan3_kernel<<<nb, 256, 0, stream>>>(packed, bpref, offsets, cursors, N);
  scatter_kernel<<<gE, 256, 0, stream>>>(rows, cols, ew, dinv, cursors, srow, scoef, E);

  const int gAgg = (N + 3) / 4;

  // ---- layer 1: h = x @ W1 ; agg = A_hat h + b1 ----
  gemm_kernel<256, 128, 64, false><<<(N + 63) / 64, 256, 0, stream>>>(x, W1, h, N, nullptr, nullptr);
  agg_kernel<128><<<gAgg, 256, 0, stream>>>(h, srow, scoef, offsets, dinv, b1, agg, N);
  stats_kernel<<<(N + 63) / 64, 256, 0, stream>>>(agg, N, sums, sumsq);
  finalize_kernel<<<1, 128, 0, stream>>>(g1, be1, sums, sumsq, alpha, beta, 1.0f / (float)N);

  // ---- layer 2: h = relu(BN(agg)) @ W2 ; agg = A_hat h + b2 ----
  gemm_kernel<128, 128, 64, true><<<(N + 63) / 64, 256, 0, stream>>>(agg, W2, h, N, alpha, beta);
  agg_kernel<128><<<gAgg, 256, 0, stream>>>(h, srow, scoef, offsets, dinv, b2, agg, N);
  stats_kernel<<<(N + 63) / 64, 256, 0, stream>>>(agg, N, sums, sumsq);
  finalize_kernel<<<1, 128, 0, stream>>>(g2, be2, sums, sumsq, alpha, beta, 1.0f / (float)N);

  // ---- layer 3: h = relu(BN(agg)) @ W3 ; out = A_hat h + b3 ----
  gemm_kernel<128, 64, 128, true><<<(N + 127) / 128, 256, 0, stream>>>(agg, W3, h, N, alpha, beta);
  agg_kernel<64><<<gAgg, 256, 0, stream>>>(h, srow, scoef, offsets, dinv, b3, (float*)d_out, N);
}

// Round 12
// 914.101 us; speedup vs baseline: 2.4422x; 2.4422x over previous
//
#include <hip/hip_runtime.h>
#include <cstddef>

// ---------------------------------------------------------------------------
// 3-layer GCN: per layer  h = A_in @ W ;  agg[c] = sum_e coef[e]*h[row_e] (+self) + b
// BN+ReLU fused into the NEXT layer's GEMM A-load.
// Edge aggregation uses a per-call counting sort by destination (no atomics in
// the hot loop). Degree+count histograms fused into one packed u64 atomic per
// edge (atomics are 32B memory-side RMW: WRITE_SIZE == 32B * n_atomics).
// GEMM: TM4xTN8, DIRECT global->LDS staging (R11 post-mortem: register
// double-buffer + launch_bounds(256,4) spilled staging arrays to scratch ->
// FETCH 51.6MB -> 1.08GB, 20x amplification, 636us/dispatch. Reverted to the
// R2-measured direct-staging structure; kept As+1 pad and split-4 ownership,
// which measured SQ_LDS_BANK_CONFLICT=0).
// ---------------------------------------------------------------------------

#define WS_ALIGN(x) (((x) + 255) & ~(size_t)255)

// ---- init: packed deg/count = 0, BN stat accumulators = 0 ------------------
__global__ __launch_bounds__(256) void init_kernel(unsigned long long* packed,
                                                   float* sums, float* sumsq,
                                                   int N) {
  int i = blockIdx.x * 256 + threadIdx.x;
  if (i < N) packed[i] = 0ull;
  if (i < 128) { sums[i] = 0.f; sumsq[i] = 0.f; }
}

// ---- per-edge: ONE packed u64 atomic = {count<<40 | fixedpoint(w)} ---------
__global__ __launch_bounds__(256) void edge_deg_kernel(const int* __restrict__ cols,
                                                       const float* __restrict__ w,
                                                       unsigned long long* __restrict__ packed,
                                                       int E) {
  int e = blockIdx.x * 256 + threadIdx.x;
  if (e >= E) return;
  int c = cols[e];
  unsigned long long v = (1ull << 40) |
                         (unsigned long long)(unsigned int)__float2uint_rn(w[e] * 1048576.0f);
  atomicAdd(&packed[c], v);
}

__global__ __launch_bounds__(256) void dinv_kernel(const unsigned long long* __restrict__ packed,
                                                   float* __restrict__ dinv, int N) {
  int i = blockIdx.x * 256 + threadIdx.x;
  if (i < N) {
    float deg = 1.0f + (float)(packed[i] & 0xFFFFFFFFFFull) * (1.0f / 1048576.0f);
    dinv[i] = rsqrtf(deg);   // deg >= 1 always (self loop)
  }
}

// ---- 3-kernel exclusive scan of hist(=packed>>40) -> offsets (chunk=2048) --
__global__ __launch_bounds__(256) void scan1_kernel(const unsigned long long* __restrict__ packed,
                                                    int* __restrict__ bsum, int N) {
  int base = blockIdx.x * 2048 + threadIdx.x * 8;
  int s = 0;
#pragma unroll
  for (int j = 0; j < 8; ++j) { int i = base + j; if (i < N) s += (int)(packed[i] >> 40); }
  __shared__ int ls[256];
  ls[threadIdx.x] = s; __syncthreads();
  for (int st = 128; st > 0; st >>= 1) {
    if (threadIdx.x < st) ls[threadIdx.x] += ls[threadIdx.x + st];
    __syncthreads();
  }
  if (threadIdx.x == 0) bsum[blockIdx.x] = ls[0];
}

// single-wave shuffle scan (nb <= 64; nb = ceil(N/2048) = 49 for N=100K)
__global__ void scan2_kernel(const int* __restrict__ bsum, int* __restrict__ bpref,
                             int nb, int* __restrict__ offsets, int N) {
  int lane = threadIdx.x;  // 64 threads
  int mine = (lane < nb) ? bsum[lane] : 0;
  int v = mine;
  for (int st = 1; st < 64; st <<= 1) {
    int t = __shfl_up(v, st, 64);
    if (lane >= st) v += t;
  }
  if (lane < nb) bpref[lane] = v - mine;   // exclusive
  if (lane == 63) offsets[N] = v;          // total == E
}

__global__ __launch_bounds__(256) void scan3_kernel(const unsigned long long* __restrict__ packed,
                                                    const int* __restrict__ bpref,
                                                    int* __restrict__ offsets,
                                                    int* __restrict__ cursors, int N) {
  int tid = threadIdx.x;
  int base = blockIdx.x * 2048 + tid * 8;
  int v[8]; int s = 0;
#pragma unroll
  for (int j = 0; j < 8; ++j) {
    int i = base + j;
    v[j] = (i < N) ? (int)(packed[i] >> 40) : 0;
    s += v[j];
  }
  __shared__ int ls[256];
  ls[tid] = s; __syncthreads();
  for (int st = 1; st < 256; st <<= 1) {
    int t = (tid >= st) ? ls[tid - st] : 0;
    __syncthreads();
    ls[tid] += t;
    __syncthreads();
  }
  int run = bpref[blockIdx.x] + (ls[tid] - s);   // exclusive prefix for this thread
#pragma unroll
  for (int j = 0; j < 8; ++j) {
    int i = base + j;
    if (i < N) { offsets[i] = run; cursors[i] = run; run += v[j]; }
  }
}

// ---- scatter edges into CSR-by-destination, fusing coef computation --------
__global__ __launch_bounds__(256) void scatter_kernel(const int* __restrict__ rows,
                                                      const int* __restrict__ cols,
                                                      const float* __restrict__ w,
                                                      const float* __restrict__ dinv,
                                                      int* __restrict__ cursors,
                                                      int* __restrict__ srow,
                                                      float* __restrict__ scoef, int E) {
  int e = blockIdx.x * 256 + threadIdx.x;
  if (e >= E) return;
  int r = rows[e], c = cols[e];
  int pos = atomicAdd(&cursors[c], 1);
  srow[pos] = r;
  scoef[pos] = dinv[r] * w[e] * dinv[c];
}

// ---- fp32 GEMM, TM4xTN8, direct global->LDS staging, fused BN+ReLU on A ----
// Split-4 ownership on B cols so every ds_read_b128 is conflict-free (16
// addresses at 16B stride -> all 32 banks, 2-way). As row pad +1: staging
// write bank = (k+r)%32 -> <=2-way; compute read is 4-address broadcast.
template <int K, int F, int BM, bool PRO>
__global__ __launch_bounds__(256)
void gemm_kernel(const float* __restrict__ A, const float* __restrict__ W,
                 float* __restrict__ out, int M,
                 const float* __restrict__ alpha, const float* __restrict__ beta) {
  constexpr int BK = 32;
  constexpr int TM = 4, TN = 8;
  constexpr int TX = F / TN;
  constexpr int TY = BM / TM;
  static_assert(TX * TY == 256, "bad tile config");
  __shared__ float As[BK][BM + 1];   // transposed: As[k][row], padded
  __shared__ float Bs[BK][F];
  const int tid = threadIdx.x;
  const int tx = tid % TX;
  const int ty = tid / TX;
  const int row0 = blockIdx.x * BM;
  float acc[TM][TN];
#pragma unroll
  for (int m = 0; m < TM; ++m)
#pragma unroll
    for (int n = 0; n < TN; ++n) acc[m][n] = 0.f;

  const int ar = tid >> 3;         // 0..31 (row within 32-row pass)
  const int ak = (tid & 7) * 4;    // k offset (float4)

  for (int k0 = 0; k0 < K; k0 += BK) {
#pragma unroll
    for (int p = 0; p < BM / 32; ++p) {
      int r = p * 32 + ar;
      int gr = row0 + r;
      float4 v;
      if (gr < M) v = *(const float4*)(A + (size_t)gr * K + k0 + ak);
      else        v = make_float4(0.f, 0.f, 0.f, 0.f);
      if constexpr (PRO) {
        float4 al = *(const float4*)(alpha + k0 + ak);
        float4 be = *(const float4*)(beta + k0 + ak);
        v.x = fmaxf(fmaf(v.x, al.x, be.x), 0.f);
        v.y = fmaxf(fmaf(v.y, al.y, be.y), 0.f);
        v.z = fmaxf(fmaf(v.z, al.z, be.z), 0.f);
        v.w = fmaxf(fmaf(v.w, al.w, be.w), 0.f);
      }
      As[ak + 0][r] = v.x; As[ak + 1][r] = v.y;
      As[ak + 2][r] = v.z; As[ak + 3][r] = v.w;
    }
#pragma unroll
    for (int p = 0; p < (BK * F) / 1024; ++p) {
      int idx = p * 256 + tid;            // float4 index
      int kk = idx / (F / 4);
      int cc = (idx % (F / 4)) * 4;
      *(float4*)&Bs[kk][cc] = *(const float4*)(W + (size_t)(k0 + kk) * F + cc);
    }
    __syncthreads();
#pragma unroll
    for (int kk = 0; kk < BK; ++kk) {
      float a[TM], b[TN];
      *(float4*)&a[0] = *(const float4*)&As[kk][ty * 4];
      *(float4*)&b[0] = *(const float4*)&Bs[kk][tx * 4];
      *(float4*)&b[4] = *(const float4*)&Bs[kk][F / 2 + tx * 4];
#pragma unroll
      for (int m = 0; m < TM; ++m)
#pragma unroll
        for (int n = 0; n < TN; ++n)
          acc[m][n] = fmaf(a[m], b[n], acc[m][n]);
    }
    __syncthreads();
  }
#pragma unroll
  for (int m = 0; m < TM; ++m) {
    int gr = row0 + ty * 4 + m;
    if (gr < M) {
      float4* o0 = (float4*)(out + (size_t)gr * F + tx * 4);
      float4* o1 = (float4*)(out + (size_t)gr * F + F / 2 + tx * 4);
      *o0 = make_float4(acc[m][0], acc[m][1], acc[m][2], acc[m][3]);
      *o1 = make_float4(acc[m][4], acc[m][5], acc[m][6], acc[m][7]);
    }
  }
}

// ---- aggregation: one wave per destination node, CSR segment ---------------
// Random-gather over L3-resident h: latency-bound, so 4-deep edge ILP.
template <int F>
__global__ __launch_bounds__(256)
void agg_kernel(const float* __restrict__ h, const int* __restrict__ srow,
                const float* __restrict__ scoef, const int* __restrict__ off,
                const float* __restrict__ dinv, const float* __restrict__ bias,
                float* __restrict__ out, int N) {
  constexpr int VPL = F / 64;   // floats per lane (2 for F=128, 1 for F=64)
  int wid = blockIdx.x * 4 + (threadIdx.x >> 6);
  if (wid >= N) return;
  int lane = threadIdx.x & 63;
  float d = dinv[wid];
  float acc[VPL];
  {
    const float* hc = h + (size_t)wid * F;
#pragma unroll
    for (int j = 0; j < VPL; ++j)
      acc[j] = d * d * hc[lane * VPL + j] + bias[lane * VPL + j];
  }
  int s = off[wid], e = off[wid + 1];
  int i = s;
  for (; i + 4 <= e; i += 4) {
    int r0 = srow[i], r1 = srow[i + 1], r2 = srow[i + 2], r3 = srow[i + 3];
    float c0 = scoef[i], c1 = scoef[i + 1], c2 = scoef[i + 2], c3 = scoef[i + 3];
    const float* h0 = h + (size_t)r0 * F;
    const float* h1 = h + (size_t)r1 * F;
    const float* h2 = h + (size_t)r2 * F;
    const float* h3 = h + (size_t)r3 * F;
    float v0[VPL], v1[VPL], v2[VPL], v3[VPL];
#pragma unroll
    for (int j = 0; j < VPL; ++j) v0[j] = h0[lane * VPL + j];
#pragma unroll
    for (int j = 0; j < VPL; ++j) v1[j] = h1[lane * VPL + j];
#pragma unroll
    for (int j = 0; j < VPL; ++j) v2[j] = h2[lane * VPL + j];
#pragma unroll
    for (int j = 0; j < VPL; ++j) v3[j] = h3[lane * VPL + j];
#pragma unroll
    for (int j = 0; j < VPL; ++j) acc[j] = fmaf(c0, v0[j], acc[j]);
#pragma unroll
    for (int j = 0; j < VPL; ++j) acc[j] = fmaf(c1, v1[j], acc[j]);
#pragma unroll
    for (int j = 0; j < VPL; ++j) acc[j] = fmaf(c2, v2[j], acc[j]);
#pragma unroll
    for (int j = 0; j < VPL; ++j) acc[j] = fmaf(c3, v3[j], acc[j]);
  }
  for (; i < e; ++i) {
    int r0 = srow[i]; float c0 = scoef[i];
    const float* h0 = h + (size_t)r0 * F;
#pragma unroll
    for (int j = 0; j < VPL; ++j) acc[j] = fmaf(c0, h0[lane * VPL + j], acc[j]);
  }
  float* oc = out + (size_t)wid * F;
#pragma unroll
  for (int j = 0; j < VPL; ++j) oc[lane * VPL + j] = acc[j];
}

// ---- BN stats: per-block partial sums over 64 rows, atomics into 128 accs --
__global__ __launch_bounds__(256) void stats_kernel(const float* __restrict__ x, int N,
                                                    float* __restrict__ sums,
                                                    float* __restrict__ sumsq) {
  int f = threadIdx.x & 127;
  int half = threadIdx.x >> 7;   // 0 or 1
  int rend = min(N, (int)(blockIdx.x + 1) * 64);
  float s = 0.f, ss = 0.f;
  for (int r = blockIdx.x * 64 + half; r < rend; r += 2) {
    float v = x[(size_t)r * 128 + f];
    s += v; ss += v * v;
  }
  __shared__ float ls[256], lss[256];
  ls[threadIdx.x] = s; lss[threadIdx.x] = ss;
  __syncthreads();
  if (half == 0) {
    s += ls[threadIdx.x + 128];
    ss += lss[threadIdx.x + 128];
    atomicAdd(&sums[f], s);
    atomicAdd(&sumsq[f], ss);
  }
}

// ---- fold stats + g/be into per-feature alpha/beta; re-zero accumulators ---
__global__ void finalize_kernel(const float* __restrict__ g, const float* __restrict__ be,
                                float* __restrict__ sums, float* __restrict__ sumsq,
                                float* __restrict__ alpha, float* __restrict__ beta,
                                float invN) {
  int f = threadIdx.x;  // 128 threads
  float mu = sums[f] * invN;
  float var = sumsq[f] * invN - mu * mu;
  float a = g[f] * rsqrtf(var + 1e-5f);
  alpha[f] = a;
  beta[f] = be[f] - mu * a;
  sums[f] = 0.f; sumsq[f] = 0.f;   // ready for next BN layer
}

extern "C" void kernel_launch(void* const* d_in, const int* in_sizes, int n_in,
                              void* d_out, int out_size, void* d_ws, size_t ws_size,
                              hipStream_t stream) {
  const float* x   = (const float*)d_in[0];
  const int*   ei  = (const int*)d_in[1];
  const float* ew  = (const float*)d_in[2];
  const float* W1  = (const float*)d_in[3];
  const float* b1  = (const float*)d_in[4];
  const float* g1  = (const float*)d_in[5];
  const float* be1 = (const float*)d_in[6];
  const float* W2  = (const float*)d_in[7];
  const float* b2  = (const float*)d_in[8];
  const float* g2  = (const float*)d_in[9];
  const float* be2 = (const float*)d_in[10];
  const float* W3  = (const float*)d_in[11];
  const float* b3  = (const float*)d_in[12];

  const int N = in_sizes[0] / 256;
  const int E = in_sizes[2];
  const int* rows = ei;        // edge_index[0]
  const int* cols = ei + E;    // edge_index[1]

  // ---- carve workspace ----
  char* p = (char*)d_ws;
  auto carve = [&](size_t bytes) { char* q = p; p += WS_ALIGN(bytes); return (void*)q; };
  unsigned long long* packed = (unsigned long long*)carve((size_t)N * 8);
  float* dinv    = (float*)carve((size_t)N * 4);
  int*   offsets = (int*)  carve(((size_t)N + 1) * 4);
  int*   cursors = (int*)  carve((size_t)N * 4);
  int*   bsum    = (int*)  carve(256 * 4);
  int*   bpref   = (int*)  carve(256 * 4);
  int*   srow    = (int*)  carve((size_t)E * 4);
  float* scoef   = (float*)carve((size_t)E * 4);
  float* h       = (float*)carve((size_t)N * 128 * 4);
  float* agg     = (float*)carve((size_t)N * 128 * 4);
  float* sums    = (float*)carve(128 * 4);
  float* sumsq   = (float*)carve(128 * 4);
  float* alpha   = (float*)carve(128 * 4);
  float* beta    = (float*)carve(128 * 4);
  (void)ws_size; (void)n_in; (void)out_size;

  const int gN = (N + 255) / 256;
  const int gE = (E + 255) / 256;
  const int nb = (N + 2047) / 2048;   // <= 64 required by scan2 (49 for N=100K)

  // ---- shared precompute: packed deg/count, dinv, CSR-by-col sort, coef ----
  init_kernel<<<gN, 256, 0, stream>>>(packed, sums, sumsq, N);
  edge_deg_kernel<<<gE, 256, 0, stream>>>(cols, ew, packed, E);
  dinv_kernel<<<gN, 256, 0, stream>>>(packed, dinv, N);
  scan1_kernel<<<nb, 256, 0, stream>>>(packed, bsum, N);
  scan2_kernel<<<1, 64, 0, stream>>>(bsum, bpref, nb, offsets, N);
  scan3_kernel<<<nb, 256, 0, stream>>>(packed, bpref, offsets, cursors, N);
  scatter_kernel<<<gE, 256, 0, stream>>>(rows, cols, ew, dinv, cursors, srow, scoef, E);

  const int gAgg = (N + 3) / 4;

  // ---- layer 1: h = x @ W1 ; agg = A_hat h + b1 ----
  gemm_kernel<256, 128, 64, false><<<(N + 63) / 64, 256, 0, stream>>>(x, W1, h, N, nullptr, nullptr);
  agg_kernel<128><<<gAgg, 256, 0, stream>>>(h, srow, scoef, offsets, dinv, b1, agg, N);
  stats_kernel<<<(N + 63) / 64, 256, 0, stream>>>(agg, N, sums, sumsq);
  finalize_kernel<<<1, 128, 0, stream>>>(g1, be1, sums, sumsq, alpha, beta, 1.0f / (float)N);

  // ---- layer 2: h = relu(BN(agg)) @ W2 ; agg = A_hat h + b2 ----
  gemm_kernel<128, 128, 64, true><<<(N + 63) / 64, 256, 0, stream>>>(agg, W2, h, N, alpha, beta);
  agg_kernel<128><<<gAgg, 256, 0, stream>>>(h, srow, scoef, offsets, dinv, b2, agg, N);
  stats_kernel<<<(N + 63) / 64, 256, 0, stream>>>(agg, N, sums, sumsq);
  finalize_kernel<<<1, 128, 0, stream>>>(g2, be2, sums, sumsq, alpha, beta, 1.0f / (float)N);

  // ---- layer 3: h = relu(BN(agg)) @ W3 ; out = A_hat h + b3 ----
  gemm_kernel<128, 64, 128, true><<<(N + 127) / 128, 256, 0, stream>>>(agg, W3, h, N, alpha, beta);
  agg_kernel<64><<<gAgg, 256, 0, stream>>>(h, srow, scoef, offsets, dinv, b3, (float*)d_out, N);
}